// Round 8
// baseline (245.659 us; speedup 1.0000x reference)
//
#include <hip/hip_runtime.h>
#include <hip/hip_bf16.h>

// Problem constants (fixed by the reference)
#define BATCH 8
#define NPTS  4096      // N
#define CCH   128      // C
#define KNN_K 16       // K

// KNN spatial grid: 16^3 cells over [-4.6, 4.6)^3 (N(0,1) outliers clamp)
#define GD  16
#define GC  (GD * GD * GD)      // 4096 cells per batch
#define GLO (-4.6f)
#define GH  (9.2f / 16.0f)      // 0.575
#define GIH (16.0f / 9.2f)

typedef __attribute__((ext_vector_type(8))) short  bf16x8;  // 8 bf16 = 4 VGPRs
typedef __attribute__((ext_vector_type(4))) float  f32x4;   // MFMA acc

// ---------------------------------------------------------------------------
// ws layout (bytes):
//   [0)          xTb   : B*N*C bf16      = 8,388,608
//   [8388608)    Wb    : C*C  bf16       =    32,768
//   [8421376)    scale : C fp32          =       512
//   [8421888)    bias  : C fp32          =       512
//   [8422400)    pts   : B*N float4(x,y,z,s) = 524,288
//   [8946688)    knn   : B*N*K u16       = 1,048,576
//   [9995264)    Zb    : B*N*C bf16      = 8,388,608   (Z = W@x, [B,N,C])
// Grid scratch OVERLAYS Zb (zgemm writes Zb only after knn completes):
//   Zb+0         counts : u32[8*GC]  = 131,072
//   Zb+131072    fill   : u32[8*GC]  = 131,072
//   Zb+262144    starts : u32[8*GC]  = 131,072
//   Zb+393216    cellid : u32[B*N]   = 131,072
//   Zb+524288    psort  : float4[B*N]= 524,288  (w = orig-index bits)
// ---------------------------------------------------------------------------

static __device__ __forceinline__ short f2bf(float v) {
    __hip_bfloat16 h = __float2bfloat16(v);   // RNE
    return __builtin_bit_cast(short, h);
}

// LDS-tiled transpose: x [B,C,N] fp32 -> xTb [B,N,C] bf16.
__global__ __launch_bounds__(256) void transpose_kernel(
    const float* __restrict__ x, short* __restrict__ xTb)
{
    __shared__ short tile[64 * 66];
    const int tid = threadIdx.x;
    const int b   = blockIdx.x >> 7;         // 8 batches
    const int rem = blockIdx.x & 127;
    const int nt  = rem >> 1;                // 64 n-tiles of 64
    const int ct  = rem & 1;                 // 2 c-tiles of 64

    #pragma unroll
    for (int it = 0; it < 16; ++it) {
        const int idx = it * 256 + tid;
        const int cc  = idx >> 6;
        const int nn  = idx & 63;
        const float v = x[(size_t)(b * CCH + ct * 64 + cc) * NPTS + nt * 64 + nn];
        tile[cc * 66 + nn] = f2bf(v);
    }
    __syncthreads();
    #pragma unroll
    for (int it = 0; it < 16; ++it) {
        const int idx = it * 256 + tid;
        const int nn  = idx >> 6;
        const int cc  = idx & 63;
        xTb[(size_t)(b * NPTS + nt * 64 + nn) * CCH + ct * 64 + cc] = tile[cc * 66 + nn];
    }
}

// Small prep: W -> bf16; fold BN affine; xyz -> SoA float4 with |p|^2
__global__ __launch_bounds__(256) void small_prep_kernel(
    const float* __restrict__ xyz, const float* __restrict__ W,
    const float* __restrict__ gamma, const float* __restrict__ beta,
    const float* __restrict__ rmean, const float* __restrict__ rvar,
    short* __restrict__ Wb, float* __restrict__ scale, float* __restrict__ bias,
    float4* __restrict__ pts)
{
    const int t = blockIdx.x * 256 + threadIdx.x;   // grid covers B*N = 32768
    if (t < CCH * CCH) Wb[t] = f2bf(W[t]);
    if (t < CCH) {
        const float s = gamma[t] / sqrtf(rvar[t] + 1e-5f);
        scale[t] = s;
        bias[t]  = beta[t] - rmean[t] * s;
    }
    {
        #pragma clang fp contract(off)
        const float px = xyz[3 * t + 0];
        const float py = xyz[3 * t + 1];
        const float pz = xyz[3 * t + 2];
        const float s  = px * px + py * py + pz * pz;   // matches ref s = sum(xyz*xyz)
        pts[t] = make_float4(px, py, pz, s);
    }
}

// ---- grid build ----------------------------------------------------------

__global__ __launch_bounds__(256) void zero_kernel(uint4* __restrict__ p)
{
    p[blockIdx.x * 256 + threadIdx.x] = make_uint4(0, 0, 0, 0);  // 256 KB: counts+fill
}

static __device__ __forceinline__ int cell_of(float v) {
    int c = (int)floorf((v - GLO) * GIH);
    return c < 0 ? 0 : (c > GD - 1 ? GD - 1 : c);
}

__global__ __launch_bounds__(256) void hist_kernel(
    const float4* __restrict__ pts, unsigned* __restrict__ counts,
    unsigned* __restrict__ cellid)
{
    const int t = blockIdx.x * 256 + threadIdx.x;   // B*N
    const float4 p = pts[t];
    const int cell = (cell_of(p.z) * GD + cell_of(p.y)) * GD + cell_of(p.x);
    cellid[t] = (unsigned)cell;
    atomicAdd(&counts[((t >> 12) << 12) + cell], 1u);
}

// exclusive scan of 4096 cell counts per batch; one block per batch
__global__ __launch_bounds__(1024) void scan_kernel(
    const unsigned* __restrict__ counts, unsigned* __restrict__ starts)
{
    __shared__ unsigned part[1024];
    const int b = blockIdx.x, t = threadIdx.x;
    const int base = (b << 12) + t * 4;
    unsigned c0 = counts[base], c1 = counts[base + 1];
    unsigned c2 = counts[base + 2], c3 = counts[base + 3];
    part[t] = c0 + c1 + c2 + c3;
    __syncthreads();
    for (int off = 1; off < 1024; off <<= 1) {
        const unsigned v = (t >= off) ? part[t - off] : 0u;
        __syncthreads();
        part[t] += v;
        __syncthreads();
    }
    unsigned run = (t == 0) ? 0u : part[t - 1];
    starts[base]     = run; run += c0;
    starts[base + 1] = run; run += c1;
    starts[base + 2] = run; run += c2;
    starts[base + 3] = run;
}

// scatter: psort.w carries the ORIGINAL within-batch index (bit pattern);
// |p|^2 is recomputed in the knn kernel with the bit-identical expression.
__global__ __launch_bounds__(256) void scatter_kernel(
    const float4* __restrict__ pts, const unsigned* __restrict__ cellid,
    const unsigned* __restrict__ starts, unsigned* __restrict__ fill,
    float4* __restrict__ psort)
{
    const int t = blockIdx.x * 256 + threadIdx.x;   // B*N
    const unsigned idx = ((unsigned)(t >> 12) << 12) + cellid[t];
    const unsigned pos = starts[idx] + atomicAdd(&fill[idx], 1u);
    const int d = ((t >> 12) << 12) + (int)pos;
    const float4 p = pts[t];
    psort[d] = make_float4(p.x, p.y, p.z, __uint_as_float((unsigned)(t & 4095)));
}

// ---- grid KNN ------------------------------------------------------------

#define PK_(h, l) ((((unsigned long long)(h)) << 32) | (unsigned long long)(l))

// KNN v8: wave-uniform B1 + PER-GROUP repair (fix for R7's straddler bug:
// ~63% of waves contain a group whose home cell is far from lane 0's due to
// row-jumps in sorted cell order; those previously fell into the dense scan).
// Flow: (1) stream lane-0's B1 box (9 rows, metadata parallel-fetched);
// (2) for each group not provably done, reset ITS list (keep tau: valid
// upper bound on its true 16th distance), stream ITS OWN B1 (act-masked:
// inactive lanes produce d2=inf, so their ballot segments never fire and
// flush no-ops on their lists), then ITS R2 shell; (3) dense fallback only
// for genuinely unproven groups (low-density outliers, ~1-2% of waves).
// Selection machinery (append/sort16/flush, keys (mono(d2), orig_j)) is
// byte-identical to the R6/R7-verified version. d2 = (qs + cs) - 2*dot with
// qs/cs computed via the bit-identical contract-off expression used by
// small_prep, so d2 bits match the reference exactly.
__global__ __launch_bounds__(256) void knn_grid_kernel(
    const float4* __restrict__ psort, const unsigned* __restrict__ starts,
    unsigned short* __restrict__ knn)
{
    const int lane = threadIdx.x & 63;
    const int wid  = threadIdx.x >> 6;
    const int g    = lane >> 4;                 // group (query) 0..3
    const int s    = lane & 15;                 // slot within group
    const int wq   = blockIdx.x * 16 + wid * 4; // first sorted query of wave
    const int b    = wq >> 12;
    const int sp   = (wq & 4095) + g;           // this lane's sorted position
    const float4*   ps  = psort + (b << 12);
    const unsigned* cst = starts + (b << 12);

    const float4 qp = ps[sp];                   // group-uniform
    const int    qi = (int)__float_as_uint(qp.w);
    float qs;
    {
        #pragma clang fp contract(off)
        qs = qp.x * qp.x + qp.y * qp.y + qp.z * qp.z;   // == small_prep s bits
    }

    // per-group home cell + wave-uniform home (lane 0)
    const int cx = cell_of(qp.x), cy = cell_of(qp.y), cz = cell_of(qp.z);
    const int hx = __shfl(cx, 0), hy = __shfl(cy, 0), hz = __shfl(cz, 0);

    const unsigned SENT_HI = 0xFF7FFFFFu;       // mono(+3.4e38)
    const unsigned SENT_LO = 0xFFFFFFFFu;

    unsigned lhi = SENT_HI, llo = SENT_LO;      // sorted top-16 list (asc)
    float bufD = 0.f;                           // survivor buffer (slot s)
    int   bufJ = 0;
    int   cnt  = 0;                             // valid entries (group-uniform)
    float tau  = 3.4e38f;
    const int      gsh   = g << 4;
    const unsigned smask = (1u << s) - 1u;

    auto sort16 = [&](unsigned& hi, unsigned& lo) {
        #define CE_(K, J, OFF) { \
            const unsigned ohi = (unsigned)__builtin_amdgcn_ds_swizzle((int)hi, OFF); \
            const unsigned olo = (unsigned)__builtin_amdgcn_ds_swizzle((int)lo, OFF); \
            const bool olt = PK_(ohi, olo) < PK_(hi, lo); \
            const bool sel = (((s & (J)) == 0) == ((s & (K)) == 0)); \
            const bool tk  = sel ? olt : !olt; \
            hi = tk ? ohi : hi; lo = tk ? olo : lo; }
        CE_(2, 1, 0x041F)
        CE_(4, 2, 0x081F)  CE_(4, 1, 0x041F)
        CE_(8, 4, 0x101F)  CE_(8, 2, 0x081F)  CE_(8, 1, 0x041F)
        CE_(16, 8, 0x201F) CE_(16, 4, 0x101F) CE_(16, 2, 0x081F) CE_(16, 1, 0x041F)
        #undef CE_
    };

    auto refresh_tau = [&]() {
        const unsigned thi = (unsigned)__builtin_amdgcn_ds_swizzle((int)lhi, 0x01F0);
        tau = __uint_as_float((thi & 0x80000000u) ? (thi & 0x7FFFFFFFu) : ~thi);
    };

    auto flush = [&]() {
        const unsigned u = __float_as_uint(bufD);
        unsigned khi = (u & 0x80000000u) ? ~u : (u | 0x80000000u);
        unsigned klo = (unsigned)bufJ;
        const bool inval = (s >= cnt);
        khi = inval ? SENT_HI : khi;
        klo = inval ? SENT_LO : klo;
        sort16(khi, klo);
        {
            const unsigned rhi = (unsigned)__builtin_amdgcn_ds_swizzle((int)khi, 0x3C1F);
            const unsigned rlo = (unsigned)__builtin_amdgcn_ds_swizzle((int)klo, 0x3C1F);
            const bool rlt = PK_(rhi, rlo) < PK_(lhi, llo);
            lhi = rlt ? rhi : lhi; llo = rlt ? rlo : llo;
        }
        #define MC_(J, OFF) { \
            const unsigned ohi = (unsigned)__builtin_amdgcn_ds_swizzle((int)lhi, OFF); \
            const unsigned olo = (unsigned)__builtin_amdgcn_ds_swizzle((int)llo, OFF); \
            const bool olt = PK_(ohi, olo) < PK_(lhi, llo); \
            const bool tk  = ((s & (J)) == 0) ? olt : !olt; \
            lhi = tk ? ohi : lhi; llo = tk ? olo : llo; }
        MC_(8, 0x201F) MC_(4, 0x101F) MC_(2, 0x081F) MC_(1, 0x041F)
        #undef MC_
        refresh_tau();
        cnt = 0;
    };

    auto append = [&](float d2v, int jov) {
        const unsigned long long mask = __ballot(d2v <= tau);
        if (mask) {
            const unsigned sub = (unsigned)((mask >> gsh) & 0xFFFFull);
            const int m = __popc(sub);
            const int lim = 15 + (m >> 4);      // m==16 needs no parking slot
            if (__any(cnt + m > lim)) flush();
            const bool surv = (sub >> s) & 1u;
            const int rank  = __popc(sub & smask);
            const int dest  = surv ? (cnt + rank) : 15;
            const int addr  = (gsh | dest) << 2;
            const int nd = __builtin_amdgcn_ds_permute(addr, __float_as_int(d2v));
            const int nj = __builtin_amdgcn_ds_permute(addr, jov);
            const bool got = (s >= cnt) & (s < cnt + m);
            bufD = got ? __int_as_float(nd) : bufD;
            bufJ = got ? nj : bufJ;
            cnt += m;
        }
    };

    // stream one contiguous sorted range [st, en); act-masked per lane
    auto stream = [&](unsigned st, unsigned en, bool act) {
        for (unsigned c0 = st; c0 < en; c0 += 16) {
            const unsigned idx = c0 + (unsigned)s;
            float d2 = __builtin_inff();
            int   jo = 0;
            if (act && idx < en) {
                const float4 p = ps[idx];
                jo = (int)__float_as_uint(p.w);
                {
                    #pragma clang fp contract(off)
                    const float cs  = p.x * p.x + p.y * p.y + p.z * p.z;
                    const float dot = qp.x * p.x + qp.y * p.y + qp.z * p.z;
                    d2 = (qs + cs) - 2.0f * dot;
                }
            }
            append(d2, jo);
        }
    };

    // stream box B1 centered at (bx,by,bz); metadata via lanes 0..8
    auto box1 = [&](int bx, int by, int bz, bool act) {
        const int x0 = max(bx - 1, 0), x1 = min(bx + 1, GD - 1);
        unsigned rst = 0, ren = 0; int rok = 0;
        if (lane < 9) {
            const int zz = bz + lane / 3 - 1;
            const int yy = by + lane % 3 - 1;
            if ((unsigned)zz < GD && (unsigned)yy < GD) {
                const int cb = (zz * GD + yy) * GD;
                rst = cst[cb + x0];
                ren = (cb + x1 + 1 < GC) ? cst[cb + x1 + 1] : (unsigned)NPTS;
                rok = 1;
            }
        }
        #pragma unroll 1
        for (int r = 0; r < 9; ++r)
            if (__shfl(rok, r)) stream(__shfl(rst, r), __shfl(ren, r), act);
    };

    // stream shell R=2 around (bx,by,bz); metadata via lanes 0..24
    auto shell2 = [&](int bx, int by, int bz, bool act) {
        const int xs0 = max(bx - 2, 0), xs1 = min(bx + 2, GD - 1);
        unsigned fst = 0, fen = 0, lst = 0, len = 0, rst2 = 0, ren2 = 0;
        int kind = 0;                           // 0=skip, 1=full row, 2=two singles
        if (lane < 25) {
            const int dz = lane / 5 - 2, dy = lane % 5 - 2;
            const int zz = bz + dz, yy = by + dy;
            if ((unsigned)zz < GD && (unsigned)yy < GD) {
                const int cb = (zz * GD + yy) * GD;
                const bool full = (dz == -2) | (dz == 2) | (dy == -2) | (dy == 2);
                if (full) {
                    kind = 1;
                    fst = cst[cb + xs0];
                    fen = (cb + xs1 + 1 < GC) ? cst[cb + xs1 + 1] : (unsigned)NPTS;
                } else {
                    kind = 2;
                    if (bx - 2 >= 0) {
                        lst = cst[cb + bx - 2];
                        len = cst[cb + bx - 1];
                    }
                    if (bx + 2 <= GD - 1) {
                        rst2 = cst[cb + bx + 2];
                        ren2 = (cb + bx + 3 < GC) ? cst[cb + bx + 3] : (unsigned)NPTS;
                    }
                }
            }
        }
        #pragma unroll 1
        for (int r = 0; r < 25; ++r) {
            const int k = __shfl(kind, r);
            if (k == 1) {
                stream(__shfl(fst, r), __shfl(fen, r), act);
            } else if (k == 2) {
                const unsigned sa = __shfl(lst, r),  sb = __shfl(len, r);
                if (sa < sb) stream(sa, sb, act);
                const unsigned sc = __shfl(rst2, r), sd = __shfl(ren2, r);
                if (sc < sd) stream(sc, sd, act);
            }
        }
    };

    // squared lower bound on distance from q to anything OUTSIDE box B_R
    // centered at cell (bx,by,bz); clamped at 0 (conservative)
    auto dmin2_box = [&](int bx, int by, int bz, int R) -> float {
        const float lx = GLO + bx * GH;
        const float ly = GLO + by * GH;
        const float lz = GLO + bz * GH;
        const float e  = (float)R * GH;
        const float m1 = fminf(qp.x - (lx - e), (lx + GH + e) - qp.x);
        const float m2 = fminf(qp.y - (ly - e), (ly + GH + e) - qp.y);
        const float m3 = fminf(qp.z - (lz - e), (lz + GH + e) - qp.z);
        const float dm = fmaxf(fminf(m1, fminf(m2, m3)) - 1e-4f, 0.f);
        return dm * dm;
    };

    // ---- phase 1: wave-uniform B1 around lane 0's home cell
    box1(hx, hy, hz, true);
    if (__any(cnt != 0)) flush();
    bool gdone = dmin2_box(hx, hy, hz, 1) > tau;

    // ---- phase 2: per-group repair
    if (!__all(gdone)) {
        #pragma unroll 1
        for (int gg = 0; gg < 4; ++gg) {
            if (__shfl((int)gdone, gg << 4)) continue;       // group proven
            const int bx = __shfl(cx, gg << 4);
            const int by = __shfl(cy, gg << 4);
            const int bz = __shfl(cz, gg << 4);
            const bool act  = (g == gg);
            const bool same = (bx == hx) & (by == hy) & (bz == hz);
            if (!same) {
                // rescan own B1: reset list (avoid duplicates), keep tau
                if (act) { lhi = SENT_HI; llo = SENT_LO; }
                box1(bx, by, bz, act);
                if (__any(cnt != 0)) flush();
                if (act) gdone = dmin2_box(bx, by, bz, 1) > tau;
            }
            if (!__shfl((int)gdone, gg << 4)) {
                shell2(bx, by, bz, act);                     // disjoint from B1
                if (__any(cnt != 0)) flush();
                if (act) gdone = dmin2_box(bx, by, bz, 2) > tau;
            }
        }
    }

    // ---- phase 3: dense fallback for unproven groups (rare outliers).
    // Reset their lists (avoid duplicates) but KEEP tau as the filter bound.
    if (!__all(gdone)) {
        const bool nd = !gdone;
        if (nd) { lhi = SENT_HI; llo = SENT_LO; }
        for (unsigned c0 = 0; c0 < (unsigned)NPTS; c0 += 16) {
            float d2 = __builtin_inff();
            int   jo = 0;
            if (nd) {
                const unsigned idx = c0 + (unsigned)s;
                const float4 p = ps[idx];
                jo = (int)__float_as_uint(p.w);
                {
                    #pragma clang fp contract(off)
                    const float cs  = p.x * p.x + p.y * p.y + p.z * p.z;
                    const float dot = qp.x * p.x + qp.y * p.y + qp.z * p.z;
                    d2 = (qs + cs) - 2.0f * dot;
                }
            }
            append(d2, jo);
        }
        if (__any(cnt != 0)) flush();
    }

    unsigned short* o = knn + ((((size_t)b << 12) + qi) << 4);
    o[s] = (unsigned short)llo;                 // j of s-th smallest (d2, j)
}

// Dense GEMM: Z[g, c] = sum_k xTb[g, k] * W[c, k], Z bf16 [B*N, C].
__global__ __launch_bounds__(256) void zgemm_kernel(
    const short* __restrict__ xTb, const short* __restrict__ Wb,
    short* __restrict__ Zb)
{
    __shared__ short sW[CCH * 136];
    const int lane = threadIdx.x & 63;
    const int wid  = threadIdx.x >> 6;
    const int kl   = lane & 15;
    const int q8   = (lane >> 4) * 8;

    #pragma unroll
    for (int it = 0; it < 8; ++it) {             // stage W: 16384 elems
        const int e = (it * 256 + threadIdx.x) * 8;
        const int r = e >> 7, c = e & 127;
        *(bf16x8*)(sW + r * 136 + c) = *(const bf16x8*)(Wb + e);
    }

    const int    G    = blockIdx.x * 64 + wid * 16 + kl;   // A-row (flat B*N)
    const size_t arow = (size_t)G * CCH;
    __syncthreads();

    const f32x4 zero = {0.f, 0.f, 0.f, 0.f};
    f32x4 acc[8];
    #pragma unroll
    for (int t = 0; t < 8; ++t) acc[t] = zero;

    #pragma unroll
    for (int kk = 0; kk < 4; ++kk) {
        const bf16x8 a = *(const bf16x8*)(xTb + arow + kk * 32 + q8);
        #pragma unroll
        for (int t = 0; t < 8; ++t) {
            const bf16x8 bf = *(const bf16x8*)(sW + (t * 16 + kl) * 136 + kk * 32 + q8);
            acc[t] = __builtin_amdgcn_mfma_f32_16x16x32_bf16(a, bf, acc[t], 0, 0, 0);
        }
    }

    const int rbase = blockIdx.x * 64 + wid * 16 + (lane >> 4) * 4;
    #pragma unroll
    for (int t = 0; t < 8; ++t)
        #pragma unroll
        for (int r = 0; r < 4; ++r)
            Zb[(size_t)(rbase + r) * CCH + t * 16 + kl] = f2bf(acc[t][r]);
}

// Gather + BN + ReLU + max-over-16, then coalesced store via LDS transpose.
__global__ __launch_bounds__(256) void gmax_kernel(
    const short* __restrict__ Zb, const unsigned short* __restrict__ knn,
    const float* __restrict__ scale, const float* __restrict__ bias,
    float* __restrict__ out)
{
    __shared__ float sm[16][132];
    const int lane = threadIdx.x & 63;
    const int wid  = threadIdx.x >> 6;
    const int n0   = blockIdx.x * 16;           // flat point base (B*N)
    const int b    = blockIdx.x >> 8;           // 256 blocks per batch
    const float s0 = scale[2 * lane],   s1 = scale[2 * lane + 1];
    const float t0 = bias[2 * lane],    t1 = bias[2 * lane + 1];

    for (int p = 0; p < 4; ++p) {
        const int n = n0 + wid * 4 + p;         // flat
        const unsigned short* kr = knn + (size_t)n * 16;
        float m0 = 0.f, m1 = 0.f;               // relu floor
        #pragma unroll
        for (int k = 0; k < 16; ++k) {
            const int r = (int)kr[k];           // within-batch row
            const unsigned v = *(const unsigned*)(Zb + ((size_t)(b * NPTS + r)) * CCH + 2 * lane);
            const float z0 = __uint_as_float(v << 16);
            const float z1 = __uint_as_float(v & 0xFFFF0000u);
            m0 = fmaxf(m0, s0 * z0 + t0);
            m1 = fmaxf(m1, s1 * z1 + t1);
        }
        sm[wid * 4 + p][2 * lane]     = m0;
        sm[wid * 4 + p][2 * lane + 1] = m1;
    }
    __syncthreads();

    const int c    = threadIdx.x & 127;
    const int half = threadIdx.x >> 7;
    float v[8];
    #pragma unroll
    for (int i = 0; i < 8; ++i) v[i] = sm[half * 8 + i][c];
    float4 f0 = {v[0], v[1], v[2], v[3]};
    float4 f1 = {v[4], v[5], v[6], v[7]};
    float* op = out + ((size_t)(b * CCH + c)) * NPTS + (n0 & 4095) + half * 8;
    *(float4*)op       = f0;
    *(float4*)(op + 4) = f1;
}

extern "C" void kernel_launch(void* const* d_in, const int* in_sizes, int n_in,
                              void* d_out, int out_size, void* d_ws, size_t ws_size,
                              hipStream_t stream)
{
    const float* xyz   = (const float*)d_in[0];
    const float* x     = (const float*)d_in[1];
    const float* W     = (const float*)d_in[2];
    const float* gamma = (const float*)d_in[3];
    const float* beta  = (const float*)d_in[4];
    const float* rmean = (const float*)d_in[5];
    const float* rvar  = (const float*)d_in[6];
    float* out = (float*)d_out;

    char* ws = (char*)d_ws;
    short*          xTb   = (short*)(ws);
    short*          Wb    = (short*)(ws + 8388608);
    float*          scale = (float*)(ws + 8421376);
    float*          bias  = (float*)(ws + 8421888);
    float4*         pts   = (float4*)(ws + 8422400);
    unsigned short* knn   = (unsigned short*)(ws + 8946688);
    short*          Zb    = (short*)(ws + 9995264);

    // grid scratch overlays Zb (consumed before zgemm writes Zb)
    char* gz = (char*)Zb;
    unsigned*       counts = (unsigned*)(gz);
    unsigned*       fill   = (unsigned*)(gz + 131072);
    unsigned*       starts = (unsigned*)(gz + 262144);
    unsigned*       cellid = (unsigned*)(gz + 393216);
    float4*         psort  = (float4*)(gz + 524288);

    transpose_kernel<<<BATCH * 64 * 2, 256, 0, stream>>>(x, xTb);
    small_prep_kernel<<<BATCH * NPTS / 256, 256, 0, stream>>>(
        xyz, W, gamma, beta, rmean, rvar, Wb, scale, bias, pts);
    zero_kernel<<<64, 256, 0, stream>>>((uint4*)gz);   // counts + fill (256 KB)
    hist_kernel<<<BATCH * NPTS / 256, 256, 0, stream>>>(pts, counts, cellid);
    scan_kernel<<<BATCH, 1024, 0, stream>>>(counts, starts);
    scatter_kernel<<<BATCH * NPTS / 256, 256, 0, stream>>>(
        pts, cellid, starts, fill, psort);
    knn_grid_kernel<<<BATCH * NPTS / 16, 256, 0, stream>>>(psort, starts, knn);
    zgemm_kernel<<<BATCH * NPTS / 64, 256, 0, stream>>>(xTb, Wb, Zb);
    gmax_kernel<<<BATCH * NPTS / 16, 256, 0, stream>>>(Zb, knn, scale, bias, out);
}

// Round 9
// 141.560 us; speedup vs baseline: 1.7354x; 1.7354x over previous
//
#include <hip/hip_runtime.h>
#include <hip/hip_bf16.h>

// Problem constants (fixed by the reference)
#define BATCH 8
#define NPTS  4096      // N
#define CCH   128      // C
#define KNN_K 16       // K

// KNN spatial grid: 16^3 cells over [-4.6, 4.6)^3 (N(0,1) outliers clamp)
#define GD  16
#define GC  (GD * GD * GD)      // 4096 cells per batch
#define GLO (-4.6f)
#define GH  (9.2f / 16.0f)      // 0.575
#define GIH (16.0f / 9.2f)

#define MAXTASK 40960           // >= 8 * (1024 + nonempty cells) upper bound

typedef __attribute__((ext_vector_type(8))) short  bf16x8;  // 8 bf16 = 4 VGPRs
typedef __attribute__((ext_vector_type(4))) float  f32x4;   // MFMA acc

// ---------------------------------------------------------------------------
// ws layout (bytes):
//   [0)          xTb   : B*N*C bf16      = 8,388,608
//   [8388608)    Wb    : C*C  bf16       =    32,768
//   [8421376)    scale : C fp32          =       512
//   [8421888)    bias  : C fp32          =       512
//   [8422400)    pts   : B*N float4(x,y,z,s) = 524,288
//   [8946688)    knn   : B*N*K u16       = 1,048,576
//   [9995264)    Zb    : B*N*C bf16      = 8,388,608   (Z = W@x, [B,N,C])
// Grid scratch OVERLAYS Zb (zgemm writes Zb only after knn completes):
//   Zb+0         counts : u32[8*GC]   = 131,072
//   Zb+131072    fill   : u32[8*GC]   = 131,072
//   Zb+262144    starts : u32[8*GC]   = 131,072
//   Zb+393216    cellid : u32[B*N]    = 131,072
//   Zb+524288    psort  : float4[B*N] = 524,288  (w = orig-index bits)
//   Zb+1048576   tasks  : u32[40960]  = 163,840
//   Zb+1212416   taskcnt: u32         (ends 1,212,420 < 8 MB)
// ---------------------------------------------------------------------------

static __device__ __forceinline__ short f2bf(float v) {
    __hip_bfloat16 h = __float2bfloat16(v);   // RNE
    return __builtin_bit_cast(short, h);
}

// LDS-tiled transpose: x [B,C,N] fp32 -> xTb [B,N,C] bf16.
__global__ __launch_bounds__(256) void transpose_kernel(
    const float* __restrict__ x, short* __restrict__ xTb)
{
    __shared__ short tile[64 * 66];
    const int tid = threadIdx.x;
    const int b   = blockIdx.x >> 7;         // 8 batches
    const int rem = blockIdx.x & 127;
    const int nt  = rem >> 1;                // 64 n-tiles of 64
    const int ct  = rem & 1;                 // 2 c-tiles of 64

    #pragma unroll
    for (int it = 0; it < 16; ++it) {
        const int idx = it * 256 + tid;
        const int cc  = idx >> 6;
        const int nn  = idx & 63;
        const float v = x[(size_t)(b * CCH + ct * 64 + cc) * NPTS + nt * 64 + nn];
        tile[cc * 66 + nn] = f2bf(v);
    }
    __syncthreads();
    #pragma unroll
    for (int it = 0; it < 16; ++it) {
        const int idx = it * 256 + tid;
        const int nn  = idx >> 6;
        const int cc  = idx & 63;
        xTb[(size_t)(b * NPTS + nt * 64 + nn) * CCH + ct * 64 + cc] = tile[cc * 66 + nn];
    }
}

// Small prep: W -> bf16; fold BN affine; xyz -> SoA float4 with |p|^2
__global__ __launch_bounds__(256) void small_prep_kernel(
    const float* __restrict__ xyz, const float* __restrict__ W,
    const float* __restrict__ gamma, const float* __restrict__ beta,
    const float* __restrict__ rmean, const float* __restrict__ rvar,
    short* __restrict__ Wb, float* __restrict__ scale, float* __restrict__ bias,
    float4* __restrict__ pts)
{
    const int t = blockIdx.x * 256 + threadIdx.x;   // grid covers B*N = 32768
    if (t < CCH * CCH) Wb[t] = f2bf(W[t]);
    if (t < CCH) {
        const float s = gamma[t] / sqrtf(rvar[t] + 1e-5f);
        scale[t] = s;
        bias[t]  = beta[t] - rmean[t] * s;
    }
    {
        #pragma clang fp contract(off)
        const float px = xyz[3 * t + 0];
        const float py = xyz[3 * t + 1];
        const float pz = xyz[3 * t + 2];
        const float s  = px * px + py * py + pz * pz;   // matches ref s = sum(xyz*xyz)
        pts[t] = make_float4(px, py, pz, s);
    }
}

// ---- grid build ----------------------------------------------------------

__global__ __launch_bounds__(256) void zero_kernel(uint4* __restrict__ p,
                                                   unsigned* __restrict__ taskcnt)
{
    p[blockIdx.x * 256 + threadIdx.x] = make_uint4(0, 0, 0, 0);  // counts+fill
    if (blockIdx.x == 0 && threadIdx.x == 0) *taskcnt = 0;
}

static __device__ __forceinline__ int cell_of(float v) {
    int c = (int)floorf((v - GLO) * GIH);
    return c < 0 ? 0 : (c > GD - 1 ? GD - 1 : c);
}

__global__ __launch_bounds__(256) void hist_kernel(
    const float4* __restrict__ pts, unsigned* __restrict__ counts,
    unsigned* __restrict__ cellid)
{
    const int t = blockIdx.x * 256 + threadIdx.x;   // B*N
    const float4 p = pts[t];
    const int cell = (cell_of(p.z) * GD + cell_of(p.y)) * GD + cell_of(p.x);
    cellid[t] = (unsigned)cell;
    atomicAdd(&counts[((t >> 12) << 12) + cell], 1u);
}

// exclusive scan of 4096 cell counts per batch; one block per batch
__global__ __launch_bounds__(1024) void scan_kernel(
    const unsigned* __restrict__ counts, unsigned* __restrict__ starts)
{
    __shared__ unsigned part[1024];
    const int b = blockIdx.x, t = threadIdx.x;
    const int base = (b << 12) + t * 4;
    unsigned c0 = counts[base], c1 = counts[base + 1];
    unsigned c2 = counts[base + 2], c3 = counts[base + 3];
    part[t] = c0 + c1 + c2 + c3;
    __syncthreads();
    for (int off = 1; off < 1024; off <<= 1) {
        const unsigned v = (t >= off) ? part[t - off] : 0u;
        __syncthreads();
        part[t] += v;
        __syncthreads();
    }
    unsigned run = (t == 0) ? 0u : part[t - 1];
    starts[base]     = run; run += c0;
    starts[base + 1] = run; run += c1;
    starts[base + 2] = run; run += c2;
    starts[base + 3] = run;
}

// scatter: psort.w carries the ORIGINAL within-batch index (bit pattern);
// |p|^2 is recomputed in the knn kernel with the bit-identical expression.
__global__ __launch_bounds__(256) void scatter_kernel(
    const float4* __restrict__ pts, const unsigned* __restrict__ cellid,
    const unsigned* __restrict__ starts, unsigned* __restrict__ fill,
    float4* __restrict__ psort)
{
    const int t = blockIdx.x * 256 + threadIdx.x;   // B*N
    const unsigned idx = ((unsigned)(t >> 12) << 12) + cellid[t];
    const unsigned pos = starts[idx] + atomicAdd(&fill[idx], 1u);
    const int d = ((t >> 12) << 12) + (int)pos;
    const float4 p = pts[t];
    psort[d] = make_float4(p.x, p.y, p.z, __uint_as_float((unsigned)(t & 4095)));
}

// task list: one task per (cell, group of <=4 queries). Task order is
// irrelevant (each query's result is independent and written once).
__global__ __launch_bounds__(256) void tasks_kernel(
    const unsigned* __restrict__ starts, unsigned* __restrict__ tasks,
    unsigned* __restrict__ taskcnt)
{
    const int t = blockIdx.x * 256 + threadIdx.x;   // 8*4096 cells
    const int cell = t & 4095;
    const unsigned st = starts[t];
    const unsigned en = (cell == GC - 1) ? (unsigned)NPTS : starts[t + 1];
    const int cnt = (int)(en - st);
    if (cnt > 0) {
        const int nt = (cnt + 3) >> 2;
        const unsigned pos = atomicAdd(taskcnt, (unsigned)nt);
        for (int i = 0; i < nt; ++i)
            tasks[pos + i] = ((unsigned)(t >> 12) << 19) | ((unsigned)cell << 7) | (unsigned)i;
    }
}

// ---- grid KNN ------------------------------------------------------------

#define PK_(h, l) ((((unsigned long long)(h)) << 32) | (unsigned long long)(l))

// KNN v9: CELL-HOMOGENEOUS waves (fix for R6-R8's straddler defect: waves
// built from consecutive sorted positions mix home cells; all repair schemes
// paid wave-wide). Each wave claims one task = (cell, 4 queries FROM THAT
// CELL). Traversal: stream home cell (R=0), then expanding rings R=1,2,...
// (wave-uniform rows; metadata parallel-fetched 64 rows/round, broadcast by
// __shfl), flush, per-query EXACT termination dmin^2(box R) > tau; break
// when all 4 proven. Rings are disjoint -> each candidate seen once. By
// R=15 the box covers the whole grid -> completeness without any fallback.
// Partial waves duplicate the cell's last query (never written). Selection
// machinery (append/sort16/flush, keys (mono(d2), orig_j)) byte-identical
// to the R6-R8-verified version; d2 = (qs+cs) - 2*dot with the bit-identical
// contract-off reference expression.
__global__ __launch_bounds__(256) void knn_grid_kernel(
    const float4* __restrict__ psort, const unsigned* __restrict__ starts,
    const unsigned* __restrict__ tasks, const unsigned* __restrict__ taskcnt,
    unsigned short* __restrict__ knn)
{
    const int lane = threadIdx.x & 63;
    const int wid  = threadIdx.x >> 6;
    const unsigned tid = blockIdx.x * 4 + wid;
    if (tid >= *taskcnt) return;
    const unsigned tk = tasks[tid];
    const int b    = (int)(tk >> 19);
    const int cell = (int)((tk >> 7) & 0xFFFu);
    const int sub  = (int)(tk & 0x7Fu);

    const int g = lane >> 4;                    // group (query) 0..3
    const int s = lane & 15;                    // slot within group
    const float4*   ps  = psort + (b << 12);
    const unsigned* cst = starts + (b << 12);

    const unsigned cs0 = cst[cell];
    const unsigned ce0 = (cell == GC - 1) ? (unsigned)NPTS : cst[cell + 1];
    const int  ccnt = (int)(ce0 - cs0);
    const int  gpos = sub * 4 + g;
    const bool act  = gpos < ccnt;              // group-uniform
    const int  sp   = (int)cs0 + (act ? gpos : ccnt - 1);

    const float4 qp = ps[sp];                   // group-uniform
    const int    qi = (int)__float_as_uint(qp.w);
    float qs;
    {
        #pragma clang fp contract(off)
        qs = qp.x * qp.x + qp.y * qp.y + qp.z * qp.z;   // == small_prep s bits
    }

    const int hx = cell & 15, hy = (cell >> 4) & 15, hz = cell >> 8;
    const float hlx = GLO + hx * GH;
    const float hly = GLO + hy * GH;
    const float hlz = GLO + hz * GH;

    const unsigned SENT_HI = 0xFF7FFFFFu;       // mono(+3.4e38)
    const unsigned SENT_LO = 0xFFFFFFFFu;

    unsigned lhi = SENT_HI, llo = SENT_LO;      // sorted top-16 list (asc)
    float bufD = 0.f;                           // survivor buffer (slot s)
    int   bufJ = 0;
    int   cnt  = 0;                             // valid entries (group-uniform)
    float tau  = 3.4e38f;
    const int      gsh   = g << 4;
    const unsigned smask = (1u << s) - 1u;

    auto sort16 = [&](unsigned& hi, unsigned& lo) {
        #define CE_(K, J, OFF) { \
            const unsigned ohi = (unsigned)__builtin_amdgcn_ds_swizzle((int)hi, OFF); \
            const unsigned olo = (unsigned)__builtin_amdgcn_ds_swizzle((int)lo, OFF); \
            const bool olt = PK_(ohi, olo) < PK_(hi, lo); \
            const bool sel = (((s & (J)) == 0) == ((s & (K)) == 0)); \
            const bool tk2 = sel ? olt : !olt; \
            hi = tk2 ? ohi : hi; lo = tk2 ? olo : lo; }
        CE_(2, 1, 0x041F)
        CE_(4, 2, 0x081F)  CE_(4, 1, 0x041F)
        CE_(8, 4, 0x101F)  CE_(8, 2, 0x081F)  CE_(8, 1, 0x041F)
        CE_(16, 8, 0x201F) CE_(16, 4, 0x101F) CE_(16, 2, 0x081F) CE_(16, 1, 0x041F)
        #undef CE_
    };

    auto refresh_tau = [&]() {
        const unsigned thi = (unsigned)__builtin_amdgcn_ds_swizzle((int)lhi, 0x01F0);
        tau = __uint_as_float((thi & 0x80000000u) ? (thi & 0x7FFFFFFFu) : ~thi);
    };

    auto flush = [&]() {
        const unsigned u = __float_as_uint(bufD);
        unsigned khi = (u & 0x80000000u) ? ~u : (u | 0x80000000u);
        unsigned klo = (unsigned)bufJ;
        const bool inval = (s >= cnt);
        khi = inval ? SENT_HI : khi;
        klo = inval ? SENT_LO : klo;
        sort16(khi, klo);
        {
            const unsigned rhi = (unsigned)__builtin_amdgcn_ds_swizzle((int)khi, 0x3C1F);
            const unsigned rlo = (unsigned)__builtin_amdgcn_ds_swizzle((int)klo, 0x3C1F);
            const bool rlt = PK_(rhi, rlo) < PK_(lhi, llo);
            lhi = rlt ? rhi : lhi; llo = rlt ? rlo : llo;
        }
        #define MC_(J, OFF) { \
            const unsigned ohi = (unsigned)__builtin_amdgcn_ds_swizzle((int)lhi, OFF); \
            const unsigned olo = (unsigned)__builtin_amdgcn_ds_swizzle((int)llo, OFF); \
            const bool olt = PK_(ohi, olo) < PK_(lhi, llo); \
            const bool tk2 = ((s & (J)) == 0) ? olt : !olt; \
            lhi = tk2 ? ohi : lhi; llo = tk2 ? olo : llo; }
        MC_(8, 0x201F) MC_(4, 0x101F) MC_(2, 0x081F) MC_(1, 0x041F)
        #undef MC_
        refresh_tau();
        cnt = 0;
    };

    auto append = [&](float d2v, int jov) {
        const unsigned long long mask = __ballot(d2v <= tau);
        if (mask) {
            const unsigned sub2 = (unsigned)((mask >> gsh) & 0xFFFFull);
            const int m = __popc(sub2);
            const int lim = 15 + (m >> 4);      // m==16 needs no parking slot
            if (__any(cnt + m > lim)) flush();
            const bool surv = (sub2 >> s) & 1u;
            const int rank  = __popc(sub2 & smask);
            const int dest  = surv ? (cnt + rank) : 15;
            const int addr  = (gsh | dest) << 2;
            const int nd = __builtin_amdgcn_ds_permute(addr, __float_as_int(d2v));
            const int nj = __builtin_amdgcn_ds_permute(addr, jov);
            const bool got = (s >= cnt) & (s < cnt + m);
            bufD = got ? __int_as_float(nd) : bufD;
            bufJ = got ? nj : bufJ;
            cnt += m;
        }
    };

    // stream one contiguous sorted range [st, en)
    auto stream = [&](unsigned st, unsigned en) {
        for (unsigned c0 = st; c0 < en; c0 += 16) {
            const unsigned idx = c0 + (unsigned)s;
            float d2 = __builtin_inff();
            int   jo = 0;
            if (idx < en) {
                const float4 p = ps[idx];
                jo = (int)__float_as_uint(p.w);
                {
                    #pragma clang fp contract(off)
                    const float cs  = p.x * p.x + p.y * p.y + p.z * p.z;
                    const float dot = qp.x * p.x + qp.y * p.y + qp.z * p.z;
                    d2 = (qs + cs) - 2.0f * dot;
                }
            }
            append(d2, jo);
        }
    };

    // stream ring R around the home cell (rows batched 64 at a time)
    auto ring = [&](int R) {
        const int W = 2 * R + 1;
        const int nrows = W * W;
        const int x0 = max(hx - R, 0), x1 = min(hx + R, GD - 1);
        for (int base = 0; base < nrows; base += 64) {
            unsigned fst = 0, fen = 0, lst = 0, len = 0, rst = 0, ren = 0;
            int kind = 0;                       // 0=skip, 1=full row, 2=two singles
            const int row = base + lane;
            if (row < nrows) {
                const int dz = row / W - R, dy = row % W - R;
                const int zz = hz + dz, yy = hy + dy;
                if ((unsigned)zz < GD && (unsigned)yy < GD) {
                    const int cb = (zz * GD + yy) * GD;
                    const bool full = (dz == -R) | (dz == R) | (dy == -R) | (dy == R);
                    if (full) {
                        kind = 1;
                        fst = cst[cb + x0];
                        fen = (cb + x1 + 1 < GC) ? cst[cb + x1 + 1] : (unsigned)NPTS;
                    } else {
                        kind = 2;
                        if (hx - R >= 0) {
                            lst = cst[cb + hx - R];
                            len = cst[cb + hx - R + 1];
                        }
                        if (hx + R <= GD - 1) {
                            rst = cst[cb + hx + R];
                            ren = (cb + hx + R + 1 < GC) ? cst[cb + hx + R + 1] : (unsigned)NPTS;
                        }
                    }
                }
            }
            const int lim = (nrows - base < 64) ? (nrows - base) : 64;
            #pragma unroll 1
            for (int r = 0; r < lim; ++r) {
                const int k = __shfl(kind, r);
                if (k == 1) {
                    stream(__shfl(fst, r), __shfl(fen, r));
                } else if (k == 2) {
                    const unsigned sa = __shfl(lst, r), sb = __shfl(len, r);
                    if (sa < sb) stream(sa, sb);
                    const unsigned sc = __shfl(rst, r), sd = __shfl(ren, r);
                    if (sc < sd) stream(sc, sd);
                }
            }
        }
    };

    // squared lower bound on distance from q to anything OUTSIDE box B_R
    auto dmin2_box = [&](int R) -> float {
        const float e  = (float)R * GH;
        const float m1 = fminf(qp.x - (hlx - e), (hlx + GH + e) - qp.x);
        const float m2 = fminf(qp.y - (hly - e), (hly + GH + e) - qp.y);
        const float m3 = fminf(qp.z - (hlz - e), (hlz + GH + e) - qp.z);
        const float dm = fmaxf(fminf(m1, fminf(m2, m3)) - 1e-4f, 0.f);
        return dm * dm;
    };

    // ---- R=0: home cell
    stream(cs0, ce0);
    // ---- expanding rings with exact per-query termination
    #pragma unroll 1
    for (int R = 1; R <= 15; ++R) {
        ring(R);
        if (__any(cnt != 0)) flush();
        if (__all(dmin2_box(R) > tau)) break;
    }
    if (__any(cnt != 0)) flush();               // safety drain

    if (act) {
        unsigned short* o = knn + ((((size_t)b << 12) + qi) << 4);
        o[s] = (unsigned short)llo;             // j of s-th smallest (d2, j)
    }
}

// Dense GEMM: Z[g, c] = sum_k xTb[g, k] * W[c, k], Z bf16 [B*N, C].
__global__ __launch_bounds__(256) void zgemm_kernel(
    const short* __restrict__ xTb, const short* __restrict__ Wb,
    short* __restrict__ Zb)
{
    __shared__ short sW[CCH * 136];
    const int lane = threadIdx.x & 63;
    const int wid  = threadIdx.x >> 6;
    const int kl   = lane & 15;
    const int q8   = (lane >> 4) * 8;

    #pragma unroll
    for (int it = 0; it < 8; ++it) {             // stage W: 16384 elems
        const int e = (it * 256 + threadIdx.x) * 8;
        const int r = e >> 7, c = e & 127;
        *(bf16x8*)(sW + r * 136 + c) = *(const bf16x8*)(Wb + e);
    }

    const int    G    = blockIdx.x * 64 + wid * 16 + kl;   // A-row (flat B*N)
    const size_t arow = (size_t)G * CCH;
    __syncthreads();

    const f32x4 zero = {0.f, 0.f, 0.f, 0.f};
    f32x4 acc[8];
    #pragma unroll
    for (int t = 0; t < 8; ++t) acc[t] = zero;

    #pragma unroll
    for (int kk = 0; kk < 4; ++kk) {
        const bf16x8 a = *(const bf16x8*)(xTb + arow + kk * 32 + q8);
        #pragma unroll
        for (int t = 0; t < 8; ++t) {
            const bf16x8 bf = *(const bf16x8*)(sW + (t * 16 + kl) * 136 + kk * 32 + q8);
            acc[t] = __builtin_amdgcn_mfma_f32_16x16x32_bf16(a, bf, acc[t], 0, 0, 0);
        }
    }

    const int rbase = blockIdx.x * 64 + wid * 16 + (lane >> 4) * 4;
    #pragma unroll
    for (int t = 0; t < 8; ++t)
        #pragma unroll
        for (int r = 0; r < 4; ++r)
            Zb[(size_t)(rbase + r) * CCH + t * 16 + kl] = f2bf(acc[t][r]);
}

// Gather + BN + ReLU + max-over-16, then coalesced store via LDS transpose.
__global__ __launch_bounds__(256) void gmax_kernel(
    const short* __restrict__ Zb, const unsigned short* __restrict__ knn,
    const float* __restrict__ scale, const float* __restrict__ bias,
    float* __restrict__ out)
{
    __shared__ float sm[16][132];
    const int lane = threadIdx.x & 63;
    const int wid  = threadIdx.x >> 6;
    const int n0   = blockIdx.x * 16;           // flat point base (B*N)
    const int b    = blockIdx.x >> 8;           // 256 blocks per batch
    const float s0 = scale[2 * lane],   s1 = scale[2 * lane + 1];
    const float t0 = bias[2 * lane],    t1 = bias[2 * lane + 1];

    for (int p = 0; p < 4; ++p) {
        const int n = n0 + wid * 4 + p;         // flat
        const unsigned short* kr = knn + (size_t)n * 16;
        float m0 = 0.f, m1 = 0.f;               // relu floor
        #pragma unroll
        for (int k = 0; k < 16; ++k) {
            const int r = (int)kr[k];           // within-batch row
            const unsigned v = *(const unsigned*)(Zb + ((size_t)(b * NPTS + r)) * CCH + 2 * lane);
            const float z0 = __uint_as_float(v << 16);
            const float z1 = __uint_as_float(v & 0xFFFF0000u);
            m0 = fmaxf(m0, s0 * z0 + t0);
            m1 = fmaxf(m1, s1 * z1 + t1);
        }
        sm[wid * 4 + p][2 * lane]     = m0;
        sm[wid * 4 + p][2 * lane + 1] = m1;
    }
    __syncthreads();

    const int c    = threadIdx.x & 127;
    const int half = threadIdx.x >> 7;
    float v[8];
    #pragma unroll
    for (int i = 0; i < 8; ++i) v[i] = sm[half * 8 + i][c];
    float4 f0 = {v[0], v[1], v[2], v[3]};
    float4 f1 = {v[4], v[5], v[6], v[7]};
    float* op = out + ((size_t)(b * CCH + c)) * NPTS + (n0 & 4095) + half * 8;
    *(float4*)op       = f0;
    *(float4*)(op + 4) = f1;
}

extern "C" void kernel_launch(void* const* d_in, const int* in_sizes, int n_in,
                              void* d_out, int out_size, void* d_ws, size_t ws_size,
                              hipStream_t stream)
{
    const float* xyz   = (const float*)d_in[0];
    const float* x     = (const float*)d_in[1];
    const float* W     = (const float*)d_in[2];
    const float* gamma = (const float*)d_in[3];
    const float* beta  = (const float*)d_in[4];
    const float* rmean = (const float*)d_in[5];
    const float* rvar  = (const float*)d_in[6];
    float* out = (float*)d_out;

    char* ws = (char*)d_ws;
    short*          xTb   = (short*)(ws);
    short*          Wb    = (short*)(ws + 8388608);
    float*          scale = (float*)(ws + 8421376);
    float*          bias  = (float*)(ws + 8421888);
    float4*         pts   = (float4*)(ws + 8422400);
    unsigned short* knn   = (unsigned short*)(ws + 8946688);
    short*          Zb    = (short*)(ws + 9995264);

    // grid scratch overlays Zb (consumed before zgemm writes Zb)
    char* gz = (char*)Zb;
    unsigned*       counts  = (unsigned*)(gz);
    unsigned*       fill    = (unsigned*)(gz + 131072);
    unsigned*       starts  = (unsigned*)(gz + 262144);
    unsigned*       cellid  = (unsigned*)(gz + 393216);
    float4*         psort   = (float4*)(gz + 524288);
    unsigned*       tasks   = (unsigned*)(gz + 1048576);
    unsigned*       taskcnt = (unsigned*)(gz + 1212416);

    transpose_kernel<<<BATCH * 64 * 2, 256, 0, stream>>>(x, xTb);
    small_prep_kernel<<<BATCH * NPTS / 256, 256, 0, stream>>>(
        xyz, W, gamma, beta, rmean, rvar, Wb, scale, bias, pts);
    zero_kernel<<<64, 256, 0, stream>>>((uint4*)gz, taskcnt);
    hist_kernel<<<BATCH * NPTS / 256, 256, 0, stream>>>(pts, counts, cellid);
    scan_kernel<<<BATCH, 1024, 0, stream>>>(counts, starts);
    scatter_kernel<<<BATCH * NPTS / 256, 256, 0, stream>>>(
        pts, cellid, starts, fill, psort);
    tasks_kernel<<<BATCH * GC / 256, 256, 0, stream>>>(starts, tasks, taskcnt);
    knn_grid_kernel<<<MAXTASK / 4, 256, 0, stream>>>(
        psort, starts, tasks, taskcnt, knn);
    zgemm_kernel<<<BATCH * NPTS / 64, 256, 0, stream>>>(xTb, Wb, Zb);
    gmax_kernel<<<BATCH * NPTS / 16, 256, 0, stream>>>(Zb, knn, scale, bias, out);
}